// Round 1
// baseline (145.819 us; speedup 1.0000x reference)
//
#include <hip/hip_runtime.h>
#include <math.h>

#define B_ 8
#define S_ 2048
#define T_TOT (B_ * S_)   // 16384 tokens
#define E_ 256
#define NQ 10
#define FF_ 1024

#define TT 64    // tokens per block
#define FK 32    // FF chunk
#define PAD 4

// ---------------------------------------------------------------------------
// K1: transpose w2 [E][FF] -> w2t [FF][E] so the main kernel's staging loads
// are coalesced float4.
// ---------------------------------------------------------------------------
__global__ __launch_bounds__(256) void w2_transpose_kernel(
    const float* __restrict__ w2, float* __restrict__ w2t)
{
    __shared__ float tile[32][33];
    int fb = blockIdx.x * 32;           // f block
    int eb = blockIdx.y * 32;           // e block
    int tx = threadIdx.x & 31;
    int ty = threadIdx.x >> 5;          // 0..7
#pragma unroll
    for (int i = 0; i < 4; ++i) {
        int e = eb + ty * 4 + i;
        tile[ty * 4 + i][tx] = w2[e * FF_ + fb + tx];   // coalesced read
    }
    __syncthreads();
#pragma unroll
    for (int i = 0; i < 4; ++i) {
        int f = fb + ty * 4 + i;
        w2t[f * E_ + eb + tx] = tile[tx][ty * 4 + i];   // coalesced write
    }
}

// ---------------------------------------------------------------------------
// K2: fused quantum-layer + MLP.
//   q[t][k>=1] = prod_{w=0..k} cos(theta_w) cos(x[t,w])
//   q[t][0]    = prod_{w=1..9} cos(theta_w) cos(x[t,w])
//   h = relu(q @ w1^T + b1); out = h @ w2^T + b2
// Block: 256 threads, 64 tokens. Per-thread out tile: 8 tokens x 8 e-cols
// (e = el..el+3 and el+128..el+131 so LDS w2 reads are lane-stride-16B).
// ---------------------------------------------------------------------------
__global__ __launch_bounds__(256) void ffq_main(
    const float* __restrict__ x,      // [T,256]
    const float* __restrict__ theta,  // [10]
    const float* __restrict__ w1,     // [1024,10]
    const float* __restrict__ b1,     // [1024]
    const float* __restrict__ w2t,    // [1024,256]
    const float* __restrict__ b2,     // [256]
    float* __restrict__ out)          // [T,256]
{
    __shared__ float q_s[TT][NQ];          // 64 x 10
    __shared__ float hs[FK][TT + PAD];     // [f][t], padded: 32 x 68
    __shared__ float ws2[FK][E_];          // 32 x 256

    const int tid   = threadIdx.x;
    const int tbase = blockIdx.x * TT;

    // ---- Phase 0: quantum expectations for this block's 64 tokens ----
    if (tid < TT) {
        int t = tbase + tid;
        float m[NQ];
#pragma unroll
        for (int w = 0; w < NQ; ++w) {
            m[w] = cosf(theta[w]) * cosf(x[t * E_ + w]);
        }
        float p = m[0];
#pragma unroll
        for (int w = 1; w < NQ; ++w) { p *= m[w]; q_s[tid][w] = p; }
        float p0 = m[1];
#pragma unroll
        for (int w = 2; w < NQ; ++w) p0 *= m[w];
        q_s[tid][0] = p0;
    }
    __syncthreads();

    float acc[8][8];
#pragma unroll
    for (int i = 0; i < 8; ++i)
#pragma unroll
        for (int j = 0; j < 8; ++j) acc[i][j] = 0.f;

    const int fl = tid & 31;         // f-lane within chunk (0..31)
    const int tg = tid >> 5;         // 0..7
    const int t0 = tg * 8;           // token sub-tile base
    const int el = (tid & 31) * 4;   // e base; second group at el+128

    for (int fc = 0; fc < FF_; fc += FK) {
        // ---- compute h chunk: h[fc+fl][t0..t0+7] ----
        {
            int f = fc + fl;
            float w1r[NQ];
#pragma unroll
            for (int w = 0; w < NQ; ++w) w1r[w] = w1[f * NQ + w];
            float bb = b1[f];
            float hv[8];
#pragma unroll
            for (int i = 0; i < 8; ++i) {
                float s = bb;
#pragma unroll
                for (int w = 0; w < NQ; ++w) s += q_s[t0 + i][w] * w1r[w];
                hv[i] = fmaxf(s, 0.f);
            }
            *(float4*)&hs[fl][t0]     = make_float4(hv[0], hv[1], hv[2], hv[3]);
            *(float4*)&hs[fl][t0 + 4] = make_float4(hv[4], hv[5], hv[6], hv[7]);
        }
        // ---- stage w2t chunk [FK][256] (coalesced float4) ----
        {
            const float4* src = (const float4*)(w2t + fc * E_);
            float4* dst = (float4*)&ws2[0][0];
#pragma unroll
            for (int k = 0; k < 8; ++k) dst[tid + k * 256] = src[tid + k * 256];
        }
        __syncthreads();

        // ---- accumulate out tile ----
#pragma unroll
        for (int f = 0; f < FK; ++f) {
            float4 h0  = *(const float4*)&hs[f][t0];       // wave-broadcast
            float4 h1  = *(const float4*)&hs[f][t0 + 4];
            float4 wv0 = *(const float4*)&ws2[f][el];      // stride-16B, clean
            float4 wv1 = *(const float4*)&ws2[f][el + 128];
            float hv[8] = {h0.x, h0.y, h0.z, h0.w, h1.x, h1.y, h1.z, h1.w};
#pragma unroll
            for (int i = 0; i < 8; ++i) {
                acc[i][0] += hv[i] * wv0.x;
                acc[i][1] += hv[i] * wv0.y;
                acc[i][2] += hv[i] * wv0.z;
                acc[i][3] += hv[i] * wv0.w;
                acc[i][4] += hv[i] * wv1.x;
                acc[i][5] += hv[i] * wv1.y;
                acc[i][6] += hv[i] * wv1.z;
                acc[i][7] += hv[i] * wv1.w;
            }
        }
        __syncthreads();
    }

    // ---- epilogue: + b2, store ----
    float4 bv0 = *(const float4*)&b2[el];
    float4 bv1 = *(const float4*)&b2[el + 128];
#pragma unroll
    for (int i = 0; i < 8; ++i) {
        int t = tbase + t0 + i;
        float4 o0 = make_float4(acc[i][0] + bv0.x, acc[i][1] + bv0.y,
                                acc[i][2] + bv0.z, acc[i][3] + bv0.w);
        float4 o1 = make_float4(acc[i][4] + bv1.x, acc[i][5] + bv1.y,
                                acc[i][6] + bv1.z, acc[i][7] + bv1.w);
        *(float4*)&out[t * E_ + el]       = o0;
        *(float4*)&out[t * E_ + el + 128] = o1;
    }
}

extern "C" void kernel_launch(void* const* d_in, const int* in_sizes, int n_in,
                              void* d_out, int out_size, void* d_ws, size_t ws_size,
                              hipStream_t stream) {
    const float* x     = (const float*)d_in[0];
    const float* theta = (const float*)d_in[1];
    const float* w1    = (const float*)d_in[2];
    const float* b1    = (const float*)d_in[3];
    const float* w2    = (const float*)d_in[4];
    const float* b2    = (const float*)d_in[5];
    float* out = (float*)d_out;
    float* w2t = (float*)d_ws;   // 1024*256*4 = 1 MB scratch

    hipLaunchKernelGGL(w2_transpose_kernel, dim3(FF_ / 32, E_ / 32), dim3(256),
                       0, stream, w2, w2t);
    hipLaunchKernelGGL(ffq_main, dim3(T_TOT / TT), dim3(256),
                       0, stream, x, theta, w1, b1, w2t, b2, out);
}

// Round 3
// 54.521 us; speedup vs baseline: 2.6746x; 2.6746x over previous
//
#include <hip/hip_runtime.h>
#include <math.h>

typedef __attribute__((ext_vector_type(8))) short bf16x8;
typedef __attribute__((ext_vector_type(4))) float f32x4;

#define T_TOT 16384
#define E_ 256
#define FF_ 1024
#define NQ 10
#define TB 64

__device__ __forceinline__ unsigned short f2bf(float f) {
    unsigned u = __builtin_bit_cast(unsigned, f);
    u = (u + 0x7FFFu + ((u >> 16) & 1u)) >> 16;
    return (unsigned short)u;
}

// ---------------------------------------------------------------------------
// Prep: build bf16 MFMA B-fragments for w2 (out-GEMM) and w1^T (h-GEMM).
//   w2f granule (kk,nt,l): j=0..7 -> w2[n=nt*16+(l&15)][k=kk*32+(l>>4)*8+j]
//     32 kk x 16 nt x 64 l = 32768 granules.
//   w1f granule (nt,l):    j=0..7 -> k=(l>>4)*8+j < 10 ? w1[n=nt*16+(l&15)][k] : 0
//     64 nt x 64 l = 4096 granules  (BUG in R2: only 2048 -> poison for f>=512)
// ---------------------------------------------------------------------------
__global__ __launch_bounds__(256) void ffq_prep(
    const float* __restrict__ w2, const float* __restrict__ w1,
    uint4* __restrict__ w2f, uint4* __restrict__ w1f)
{
    int id = blockIdx.x * 256 + threadIdx.x;
    if (id < 32768) {
        int l = id & 63, nt = (id >> 6) & 15, kk = id >> 10;
        int n  = nt * 16 + (l & 15);
        int k0 = kk * 32 + (l >> 4) * 8;
        const float4* s = (const float4*)(w2 + (size_t)n * FF_ + k0);
        float4 a = s[0], b = s[1];
        uint4 v;
        v.x = f2bf(a.x) | ((unsigned)f2bf(a.y) << 16);
        v.y = f2bf(a.z) | ((unsigned)f2bf(a.w) << 16);
        v.z = f2bf(b.x) | ((unsigned)f2bf(b.y) << 16);
        v.w = f2bf(b.z) | ((unsigned)f2bf(b.w) << 16);
        w2f[id] = v;
    } else if (id < 32768 + 4096) {
        int id2 = id - 32768;
        int l = id2 & 63, nt = id2 >> 6;          // nt = 0..63 (all 64 f-tiles)
        int n = nt * 16 + (l & 15);
        int g = l >> 4;
        unsigned short o[8];
#pragma unroll
        for (int j = 0; j < 8; ++j) {
            int k = g * 8 + j;
            o[j] = (k < NQ) ? f2bf(w1[n * NQ + k]) : (unsigned short)0;
        }
        uint4 v;
        v.x = o[0] | ((unsigned)o[1] << 16);
        v.y = o[2] | ((unsigned)o[3] << 16);
        v.z = o[4] | ((unsigned)o[5] << 16);
        v.w = o[6] | ((unsigned)o[7] << 16);
        w1f[id2] = v;
    }
}

// ---------------------------------------------------------------------------
// Fused: analytic quantum layer -> h-GEMM (MFMA, K=10 pad 32) -> out-GEMM
// (MFMA, K=1024). 512 threads = 8 waves: (wm 0..3 token group) x (wn 0..1
// FF half). h stored in LDS in exact out-GEMM A-fragment order.
// ---------------------------------------------------------------------------
__global__ __launch_bounds__(512) void ffq_mfma(
    const float* __restrict__ x, const float* __restrict__ theta,
    const float* __restrict__ b1, const float* __restrict__ b2,
    const bf16x8* __restrict__ w1f, const bf16x8* __restrict__ w2f,
    float* __restrict__ out)
{
    __shared__ unsigned short hs[TB * FF_];   // 128 KiB, frag-granule layout

    const int tid = threadIdx.x;
    const int l   = tid & 63;
    const int wv  = tid >> 6;     // 0..7
    const int wm  = wv >> 1;      // token group 0..3
    const int wn  = wv & 1;       // FF half 0..1
    const int lr  = l & 15;
    const int g   = l >> 4;
    const int tb  = blockIdx.x * TB;

    // ---- analytic quantum expvals for this lane's token ----
    const int t = tb + wm * 16 + lr;
    float xv[NQ];
    {
        float4 a = *(const float4*)(x + (size_t)t * E_);
        float4 b = *(const float4*)(x + (size_t)t * E_ + 4);
        float2 c = *(const float2*)(x + (size_t)t * E_ + 8);
        xv[0]=a.x; xv[1]=a.y; xv[2]=a.z; xv[3]=a.w;
        xv[4]=b.x; xv[5]=b.y; xv[6]=b.z; xv[7]=b.w;
        xv[8]=c.x; xv[9]=c.y;
    }
    float mm[NQ];
#pragma unroll
    for (int w = 0; w < NQ; ++w) mm[w] = cosf(theta[w]) * cosf(xv[w]);
    float qv[NQ];
    {
        float p = mm[0];
#pragma unroll
        for (int w = 1; w < NQ; ++w) { p *= mm[w]; qv[w] = p; }
        float p0 = mm[1];
#pragma unroll
        for (int w = 2; w < NQ; ++w) p0 *= mm[w];
        qv[0] = p0;
    }
    // q B-fragment: lane holds q[t][k], k = g*8+j (zero-padded past k=9)
    bf16x8 qf;
#pragma unroll
    for (int j = 0; j < 8; ++j) {
        int k = g * 8 + j;
        float v = (k < NQ) ? qv[k] : 0.f;
        qf[j] = (short)f2bf(v);
    }

    // ---- h = relu(w1 . q^T + b1): D'[f][t] per wave over 32 f-tiles ----
#pragma unroll 4
    for (int nt = 0; nt < 32; ++nt) {
        int ntg = wn * 32 + nt;
        bf16x8 wf = w1f[ntg * 64 + l];
        f32x4 d = {0.f, 0.f, 0.f, 0.f};
        d = __builtin_amdgcn_mfma_f32_16x16x32_bf16(wf, qf, d, 0, 0, 0);
        int f0 = wn * 512 + nt * 16 + g * 4;           // rows f0..f0+3, col t
        float4 bb = *(const float4*)(b1 + f0);
        unsigned p0 = f2bf(fmaxf(d[0] + bb.x, 0.f))
                    | ((unsigned)f2bf(fmaxf(d[1] + bb.y, 0.f)) << 16);
        unsigned p1 = f2bf(fmaxf(d[2] + bb.z, 0.f))
                    | ((unsigned)f2bf(fmaxf(d[3] + bb.w, 0.f)) << 16);
        // store h[t][f0..f0+3] into A-frag granule layout:
        // granule(t,f) = ((t>>4)*32 + (f>>5))*64 + (t&15) + (((f>>3)&3)<<4)
        int gran = (wm * 32 + (f0 >> 5)) * 64 + lr + (((f0 >> 3) & 3) << 4);
        unsigned byteoff = (unsigned)gran * 16u + (unsigned)(f0 & 7) * 2u;
        *(uint2*)((char*)hs + byteoff) = make_uint2(p0, p1);
    }
    __syncthreads();

    // ---- out = h @ w2^T + b2 : wave tile 16 tok x 128 cols ----
    f32x4 acc[8];
#pragma unroll
    for (int n = 0; n < 8; ++n) acc[n] = (f32x4){0.f, 0.f, 0.f, 0.f};

    const bf16x8* hfr = (const bf16x8*)hs;
    for (int kk = 0; kk < 32; ++kk) {
        bf16x8 af = hfr[(wm * 32 + kk) * 64 + l];      // ds_read_b128
#pragma unroll
        for (int n = 0; n < 8; ++n) {
            bf16x8 bf = w2f[(kk * 16 + wn * 8 + n) * 64 + l];  // L2-hit dwordx4
            acc[n] = __builtin_amdgcn_mfma_f32_16x16x32_bf16(af, bf, acc[n], 0, 0, 0);
        }
    }

    // ---- epilogue: + b2, store fp32 ----
#pragma unroll
    for (int n = 0; n < 8; ++n) {
        int col = wn * 128 + n * 16 + lr;
        float bbv = b2[col];
#pragma unroll
        for (int r = 0; r < 4; ++r) {
            int tr = tb + wm * 16 + g * 4 + r;
            out[(size_t)tr * E_ + col] = acc[n][r] + bbv;
        }
    }
}

extern "C" void kernel_launch(void* const* d_in, const int* in_sizes, int n_in,
                              void* d_out, int out_size, void* d_ws, size_t ws_size,
                              hipStream_t stream) {
    const float* x     = (const float*)d_in[0];
    const float* theta = (const float*)d_in[1];
    const float* w1    = (const float*)d_in[2];
    const float* b1    = (const float*)d_in[3];
    const float* w2    = (const float*)d_in[4];
    const float* b2    = (const float*)d_in[5];
    float* out = (float*)d_out;

    uint4* w2f = (uint4*)d_ws;                          // 512 KiB
    uint4* w1f = (uint4*)((char*)d_ws + 512 * 1024);    // 64 KiB

    hipLaunchKernelGGL(ffq_prep, dim3(144), dim3(256), 0, stream,
                       w2, w1, w2f, w1f);
    hipLaunchKernelGGL(ffq_mfma, dim3(T_TOT / TB), dim3(512), 0, stream,
                       x, theta, b1, b2,
                       (const bf16x8*)w1f, (const bf16x8*)w2f, out);
}

// Round 4
// 32.971 us; speedup vs baseline: 4.4226x; 1.6536x over previous
//
#include <hip/hip_runtime.h>
#include <math.h>

typedef __attribute__((ext_vector_type(8))) short bf16x8;
typedef __attribute__((ext_vector_type(4))) float f32x4;

#define T_TOT 16384
#define E_ 256
#define FF_ 1024
#define NQ 10
#define TB 64
#define CH 256           // f per chunk
#define NCHUNK (FF_ / CH)

__device__ __forceinline__ unsigned short f2bf(float f) {
    unsigned u = __builtin_bit_cast(unsigned, f);
    u = (u + 0x7FFFu + ((u >> 16) & 1u)) >> 16;
    return (unsigned short)u;
}

// ---------------------------------------------------------------------------
// Prep: bf16 MFMA B-fragments for w2 (out-GEMM) and w1^T (h-GEMM).
//   w2f granule (kk,nt,l): j=0..7 -> w2[n=nt*16+(l&15)][k=kk*32+(l>>4)*8+j]
//   w1f granule (nt,l):    j=0..7 -> k=(l>>4)*8+j < 10 ? w1[n][k] : 0
// ---------------------------------------------------------------------------
__global__ __launch_bounds__(256) void ffq_prep(
    const float* __restrict__ w2, const float* __restrict__ w1,
    uint4* __restrict__ w2f, uint4* __restrict__ w1f)
{
    int id = blockIdx.x * 256 + threadIdx.x;
    if (id < 32768) {
        int l = id & 63, nt = (id >> 6) & 15, kk = id >> 10;
        int n  = nt * 16 + (l & 15);
        int k0 = kk * 32 + (l >> 4) * 8;
        const float4* s = (const float4*)(w2 + (size_t)n * FF_ + k0);
        float4 a = s[0], b = s[1];
        uint4 v;
        v.x = f2bf(a.x) | ((unsigned)f2bf(a.y) << 16);
        v.y = f2bf(a.z) | ((unsigned)f2bf(a.w) << 16);
        v.z = f2bf(b.x) | ((unsigned)f2bf(b.y) << 16);
        v.w = f2bf(b.z) | ((unsigned)f2bf(b.w) << 16);
        w2f[id] = v;
    } else if (id < 32768 + 4096) {
        int id2 = id - 32768;
        int l = id2 & 63, nt = id2 >> 6;          // 64 f-tiles
        int n = nt * 16 + (l & 15);
        int g = l >> 4;
        unsigned short o[8];
#pragma unroll
        for (int j = 0; j < 8; ++j) {
            int k = g * 8 + j;
            o[j] = (k < NQ) ? f2bf(w1[n * NQ + k]) : (unsigned short)0;
        }
        uint4 v;
        v.x = o[0] | ((unsigned)o[1] << 16);
        v.y = o[2] | ((unsigned)o[3] << 16);
        v.z = o[4] | ((unsigned)o[5] << 16);
        v.w = o[6] | ((unsigned)o[7] << 16);
        w1f[id2] = v;
    }
}

// ---------------------------------------------------------------------------
// Fused kernel, v2:
//  - 512 thr = 8 waves; wave wv owns out-cols wv*32..wv*32+31 (nt=2), ALL 64
//    tokens (mt=4)  -> zero B redundancy in the block.
//  - hs staged per 256-f chunk (32 KiB); q staged once in LDS frag granules.
//  - __launch_bounds__(512,4): VGPR<=128 -> 2 blocks/CU, 4 waves/SIMD.
// ---------------------------------------------------------------------------
__global__ __launch_bounds__(512, 4) void ffq_mfma(
    const float* __restrict__ x, const float* __restrict__ theta,
    const float* __restrict__ b1, const float* __restrict__ b2,
    const bf16x8* __restrict__ w1f, const bf16x8* __restrict__ w2f,
    float* __restrict__ out)
{
    __shared__ unsigned short q_s[4 * 64 * 8];     // 4 tt granules, 4 KiB
    __shared__ unsigned short hs[TB * CH];         // 64 tok x 256 f, 32 KiB

    const int tid = threadIdx.x;
    const int l   = tid & 63;
    const int wv  = tid >> 6;     // 0..7
    const int lr  = l & 15;
    const int g   = l >> 4;       // 0..3
    const int tb  = blockIdx.x * TB;

    // ---- Phase 0: threads 0..63 compute q for the block's 64 tokens and
    //      write B-frag granules (zeroing k>=16 slots). ----
    if (tid < TB) {
        const int t = tb + tid;
        float xv[NQ];
        {
            float4 a = *(const float4*)(x + (size_t)t * E_);
            float4 b = *(const float4*)(x + (size_t)t * E_ + 4);
            float2 c = *(const float2*)(x + (size_t)t * E_ + 8);
            xv[0]=a.x; xv[1]=a.y; xv[2]=a.z; xv[3]=a.w;
            xv[4]=b.x; xv[5]=b.y; xv[6]=b.z; xv[7]=b.w;
            xv[8]=c.x; xv[9]=c.y;
        }
        float mm[NQ];
#pragma unroll
        for (int w = 0; w < NQ; ++w) mm[w] = cosf(theta[w]) * cosf(xv[w]);
        float qv[NQ];
        {
            float p = mm[0];
#pragma unroll
            for (int w = 1; w < NQ; ++w) { p *= mm[w]; qv[w] = p; }
            float p0 = mm[1];
#pragma unroll
            for (int w = 2; w < NQ; ++w) p0 *= mm[w];
            qv[0] = p0;
        }
        unsigned short qb[10];
#pragma unroll
        for (int k = 0; k < NQ; ++k) qb[k] = f2bf(qv[k]);
        uint4 s0, s1;
        s0.x = qb[0] | ((unsigned)qb[1] << 16);
        s0.y = qb[2] | ((unsigned)qb[3] << 16);
        s0.z = qb[4] | ((unsigned)qb[5] << 16);
        s0.w = qb[6] | ((unsigned)qb[7] << 16);
        s1.x = qb[8] | ((unsigned)qb[9] << 16);
        s1.y = 0; s1.z = 0; s1.w = 0;
        int tt = tid >> 4, r = tid & 15;
        uint4* base = (uint4*)q_s + tt * 64;
        base[r]      = s0;                       // slot g=0 (k 0..7)
        base[16 + r] = s1;                       // slot g=1 (k 8..9, pad)
        base[32 + r] = make_uint4(0, 0, 0, 0);   // slot g=2
        base[48 + r] = make_uint4(0, 0, 0, 0);   // slot g=3
    }
    __syncthreads();

    // q fragments for all 4 token-tiles (register-resident)
    bf16x8 qf[4];
#pragma unroll
    for (int tt = 0; tt < 4; ++tt) qf[tt] = ((const bf16x8*)q_s)[tt * 64 + l];

    f32x4 acc[4][2];
#pragma unroll
    for (int tt = 0; tt < 4; ++tt)
#pragma unroll
        for (int nn = 0; nn < 2; ++nn) acc[tt][nn] = (f32x4){0.f,0.f,0.f,0.f};

    for (int c = 0; c < NCHUNK; ++c) {
        // ---- h-phase: wave wv computes local f-tiles wv*2, wv*2+1 ----
#pragma unroll
        for (int fi = 0; fi < 2; ++fi) {
            const int ftl = wv * 2 + fi;          // local f-tile 0..15
            const int ntg = c * 16 + ftl;         // global f-tile
            bf16x8 wf = w1f[ntg * 64 + l];
            const int f0 = ntg * 16 + g * 4;      // global f base for D rows
            float4 bb = *(const float4*)(b1 + f0);
            const int fl = ftl * 16 + g * 4;      // f local in chunk
            const int s  = (fl & 31) >> 3;        // k-slot in A granule
            const int gran = ((fl >> 5)) * 64 + lr + 16 * s;  // + tt*8*64 below
#pragma unroll
            for (int tt = 0; tt < 4; ++tt) {
                f32x4 d = {0.f, 0.f, 0.f, 0.f};
                d = __builtin_amdgcn_mfma_f32_16x16x32_bf16(wf, qf[tt], d, 0, 0, 0);
                unsigned p0 = f2bf(fmaxf(d[0] + bb.x, 0.f))
                            | ((unsigned)f2bf(fmaxf(d[1] + bb.y, 0.f)) << 16);
                unsigned p1 = f2bf(fmaxf(d[2] + bb.z, 0.f))
                            | ((unsigned)f2bf(fmaxf(d[3] + bb.w, 0.f)) << 16);
                unsigned byteoff = (unsigned)(tt * 512 + gran) * 16u
                                 + (unsigned)(fl & 7) * 2u;
                *(uint2*)((char*)hs + byteoff) = make_uint2(p0, p1);
            }
        }
        __syncthreads();

        // ---- out-phase: 8 kk steps; A from LDS (4 granules), B from L1 ----
#pragma unroll 2
        for (int kkl = 0; kkl < 8; ++kkl) {
            const int kk = c * 8 + kkl;
            bf16x8 af[4];
#pragma unroll
            for (int tt = 0; tt < 4; ++tt)
                af[tt] = ((const bf16x8*)hs)[(tt * 8 + kkl) * 64 + l];
#pragma unroll
            for (int nn = 0; nn < 2; ++nn) {
                const int n = wv * 2 + nn;
                bf16x8 bf = w2f[(kk * 16 + n) * 64 + l];
#pragma unroll
                for (int tt = 0; tt < 4; ++tt)
                    acc[tt][nn] = __builtin_amdgcn_mfma_f32_16x16x32_bf16(
                        af[tt], bf, acc[tt][nn], 0, 0, 0);
            }
        }
        __syncthreads();
    }

    // ---- epilogue: + b2, store fp32 ----
#pragma unroll
    for (int nn = 0; nn < 2; ++nn) {
        const int col = wv * 32 + nn * 16 + lr;
        const float bbv = b2[col];
#pragma unroll
        for (int tt = 0; tt < 4; ++tt) {
#pragma unroll
            for (int r = 0; r < 4; ++r) {
                int tr = tb + tt * 16 + g * 4 + r;
                out[(size_t)tr * E_ + col] = acc[tt][nn][r] + bbv;
            }
        }
    }
}

extern "C" void kernel_launch(void* const* d_in, const int* in_sizes, int n_in,
                              void* d_out, int out_size, void* d_ws, size_t ws_size,
                              hipStream_t stream) {
    const float* x     = (const float*)d_in[0];
    const float* theta = (const float*)d_in[1];
    const float* w1    = (const float*)d_in[2];
    const float* b1    = (const float*)d_in[3];
    const float* w2    = (const float*)d_in[4];
    const float* b2    = (const float*)d_in[5];
    float* out = (float*)d_out;

    uint4* w2f = (uint4*)d_ws;                          // 512 KiB
    uint4* w1f = (uint4*)((char*)d_ws + 512 * 1024);    // 64 KiB

    hipLaunchKernelGGL(ffq_prep, dim3(144), dim3(256), 0, stream,
                       w2, w1, w2f, w1f);
    hipLaunchKernelGGL(ffq_mfma, dim3(T_TOT / TB), dim3(512), 0, stream,
                       x, theta, b1, b2,
                       (const bf16x8*)w1f, (const bf16x8*)w2f, out);
}

// Round 5
// 28.260 us; speedup vs baseline: 5.1598x; 1.1667x over previous
//
#include <hip/hip_runtime.h>
#include <math.h>

typedef __attribute__((ext_vector_type(8))) short bf16x8;
typedef __attribute__((ext_vector_type(4))) float f32x4;

#define T_TOT 16384
#define E_ 256
#define FF_ 1024
#define NQ 10
#define TB 64
#define CH 256           // f per chunk
#define NCHUNK (FF_ / CH)

__device__ __forceinline__ unsigned short f2bf(float f) {
    unsigned u = __builtin_bit_cast(unsigned, f);
    u = (u + 0x7FFFu + ((u >> 16) & 1u)) >> 16;
    return (unsigned short)u;
}

// ---------------------------------------------------------------------------
// Prep: bf16 MFMA B-fragments for w2 (out-GEMM) and w1^T (h-GEMM).
//   w2f granule (kk,nt,l): j=0..7 -> w2[n=nt*16+(l&15)][k=kk*32+(l>>4)*8+j]
//   w1f granule (nt,l):    j=0..7 -> k=(l>>4)*8+j < 10 ? w1[n][k] : 0
// ---------------------------------------------------------------------------
__global__ __launch_bounds__(256) void ffq_prep(
    const float* __restrict__ w2, const float* __restrict__ w1,
    uint4* __restrict__ w2f, uint4* __restrict__ w1f)
{
    int id = blockIdx.x * 256 + threadIdx.x;
    if (id < 32768) {
        int l = id & 63, nt = (id >> 6) & 15, kk = id >> 10;
        int n  = nt * 16 + (l & 15);
        int k0 = kk * 32 + (l >> 4) * 8;
        const float4* s = (const float4*)(w2 + (size_t)n * FF_ + k0);
        float4 a = s[0], b = s[1];
        uint4 v;
        v.x = f2bf(a.x) | ((unsigned)f2bf(a.y) << 16);
        v.y = f2bf(a.z) | ((unsigned)f2bf(a.w) << 16);
        v.z = f2bf(b.x) | ((unsigned)f2bf(b.y) << 16);
        v.w = f2bf(b.z) | ((unsigned)f2bf(b.w) << 16);
        w2f[id] = v;
    } else if (id < 32768 + 4096) {
        int id2 = id - 32768;
        int l = id2 & 63, nt = id2 >> 6;          // 64 f-tiles
        int n = nt * 16 + (l & 15);
        int g = l >> 4;
        unsigned short o[8];
#pragma unroll
        for (int j = 0; j < 8; ++j) {
            int k = g * 8 + j;
            o[j] = (k < NQ) ? f2bf(w1[n * NQ + k]) : (unsigned short)0;
        }
        uint4 v;
        v.x = o[0] | ((unsigned)o[1] << 16);
        v.y = o[2] | ((unsigned)o[3] << 16);
        v.z = o[4] | ((unsigned)o[5] << 16);
        v.w = o[6] | ((unsigned)o[7] << 16);
        w1f[id2] = v;
    }
}

// ---------------------------------------------------------------------------
// Fused kernel v3:
//  - grid 512 = 256 token-tiles x 2 col-halves; block = 64 tok x 128 cols.
//  - 8 waves; wave = 64 tok (mt=4) x 16 cols (nt=1). B zero-redundant.
//  - 36 KiB LDS, __launch_bounds__(512,4) -> 2 blocks/CU = 4 waves/SIMD.
//  - explicit depth-1 register prefetch of the B granule across the kk loop.
// ---------------------------------------------------------------------------
__global__ __launch_bounds__(512, 4) void ffq_mfma(
    const float* __restrict__ x, const float* __restrict__ theta,
    const float* __restrict__ b1, const float* __restrict__ b2,
    const bf16x8* __restrict__ w1f, const bf16x8* __restrict__ w2f,
    float* __restrict__ out)
{
    __shared__ unsigned short q_s[4 * 64 * 8];     // 4 KiB
    __shared__ unsigned short hs[TB * CH];         // 32 KiB

    const int tid  = threadIdx.x;
    const int l    = tid & 63;
    const int wv   = tid >> 6;           // 0..7
    const int lr   = l & 15;
    const int g    = l >> 4;             // 0..3
    const int chb  = blockIdx.x & 1;     // col half 0/1
    const int tb   = (blockIdx.x >> 1) * TB;
    const int ncol = chb * 8 + wv;       // global col-tile 0..15

    // ---- Phase 0: threads 0..63 compute q, write B-frag granules ----
    if (tid < TB) {
        const int t = tb + tid;
        float xv[NQ];
        {
            float4 a = *(const float4*)(x + (size_t)t * E_);
            float4 b = *(const float4*)(x + (size_t)t * E_ + 4);
            float2 c = *(const float2*)(x + (size_t)t * E_ + 8);
            xv[0]=a.x; xv[1]=a.y; xv[2]=a.z; xv[3]=a.w;
            xv[4]=b.x; xv[5]=b.y; xv[6]=b.z; xv[7]=b.w;
            xv[8]=c.x; xv[9]=c.y;
        }
        float mm[NQ];
#pragma unroll
        for (int w = 0; w < NQ; ++w) mm[w] = cosf(theta[w]) * cosf(xv[w]);
        float qv[NQ];
        {
            float p = mm[0];
#pragma unroll
            for (int w = 1; w < NQ; ++w) { p *= mm[w]; qv[w] = p; }
            float p0 = mm[1];
#pragma unroll
            for (int w = 2; w < NQ; ++w) p0 *= mm[w];
            qv[0] = p0;
        }
        unsigned short qb[10];
#pragma unroll
        for (int k = 0; k < NQ; ++k) qb[k] = f2bf(qv[k]);
        uint4 s0, s1;
        s0.x = qb[0] | ((unsigned)qb[1] << 16);
        s0.y = qb[2] | ((unsigned)qb[3] << 16);
        s0.z = qb[4] | ((unsigned)qb[5] << 16);
        s0.w = qb[6] | ((unsigned)qb[7] << 16);
        s1.x = qb[8] | ((unsigned)qb[9] << 16);
        s1.y = 0; s1.z = 0; s1.w = 0;
        int tt = tid >> 4, r = tid & 15;
        uint4* base = (uint4*)q_s + tt * 64;
        base[r]      = s0;
        base[16 + r] = s1;
        base[32 + r] = make_uint4(0, 0, 0, 0);
        base[48 + r] = make_uint4(0, 0, 0, 0);
    }
    __syncthreads();

    bf16x8 qf[4];
#pragma unroll
    for (int tt = 0; tt < 4; ++tt) qf[tt] = ((const bf16x8*)q_s)[tt * 64 + l];

    f32x4 acc[4];
#pragma unroll
    for (int tt = 0; tt < 4; ++tt) acc[tt] = (f32x4){0.f, 0.f, 0.f, 0.f};

    // depth-1 B prefetch (register double-buffer, survives barriers)
    bf16x8 bcur = w2f[(0 * 16 + ncol) * 64 + l];

    for (int c = 0; c < NCHUNK; ++c) {
        // ---- h-phase: wave wv computes local f-tiles wv*2, wv*2+1 ----
#pragma unroll
        for (int fi = 0; fi < 2; ++fi) {
            const int ftl = wv * 2 + fi;          // local f-tile 0..15
            const int ntg = c * 16 + ftl;         // global f-tile
            bf16x8 wf = w1f[ntg * 64 + l];
            const int f0 = ntg * 16 + g * 4;
            float4 bb = *(const float4*)(b1 + f0);
            const int fl = ftl * 16 + g * 4;
            const int s  = (fl & 31) >> 3;
            const int gran = (fl >> 5) * 64 + lr + 16 * s;
#pragma unroll
            for (int tt = 0; tt < 4; ++tt) {
                f32x4 d = {0.f, 0.f, 0.f, 0.f};
                d = __builtin_amdgcn_mfma_f32_16x16x32_bf16(wf, qf[tt], d, 0, 0, 0);
                unsigned p0 = f2bf(fmaxf(d[0] + bb.x, 0.f))
                            | ((unsigned)f2bf(fmaxf(d[1] + bb.y, 0.f)) << 16);
                unsigned p1 = f2bf(fmaxf(d[2] + bb.z, 0.f))
                            | ((unsigned)f2bf(fmaxf(d[3] + bb.w, 0.f)) << 16);
                unsigned byteoff = (unsigned)(tt * 512 + gran) * 16u
                                 + (unsigned)(fl & 7) * 2u;
                *(uint2*)((char*)hs + byteoff) = make_uint2(p0, p1);
            }
        }
        __syncthreads();

        // ---- out-phase: 8 kk steps, B prefetched 1 ahead ----
#pragma unroll
        for (int kkl = 0; kkl < 8; ++kkl) {
            const int kk  = c * 8 + kkl;
            const int kkn = (kk + 1 < 32) ? kk + 1 : 31;
            bf16x8 bnext = w2f[(kkn * 16 + ncol) * 64 + l];
            bf16x8 af[4];
#pragma unroll
            for (int tt = 0; tt < 4; ++tt)
                af[tt] = ((const bf16x8*)hs)[(tt * 8 + kkl) * 64 + l];
#pragma unroll
            for (int tt = 0; tt < 4; ++tt)
                acc[tt] = __builtin_amdgcn_mfma_f32_16x16x32_bf16(
                    af[tt], bcur, acc[tt], 0, 0, 0);
            bcur = bnext;
        }
        __syncthreads();
    }

    // ---- epilogue: + b2, store fp32 ----
    {
        const int col = ncol * 16 + lr;
        const float bbv = b2[col];
#pragma unroll
        for (int tt = 0; tt < 4; ++tt) {
#pragma unroll
            for (int r = 0; r < 4; ++r) {
                int tr = tb + tt * 16 + g * 4 + r;
                out[(size_t)tr * E_ + col] = acc[tt][r] + bbv;
            }
        }
    }
}

extern "C" void kernel_launch(void* const* d_in, const int* in_sizes, int n_in,
                              void* d_out, int out_size, void* d_ws, size_t ws_size,
                              hipStream_t stream) {
    const float* x     = (const float*)d_in[0];
    const float* theta = (const float*)d_in[1];
    const float* w1    = (const float*)d_in[2];
    const float* b1    = (const float*)d_in[3];
    const float* w2    = (const float*)d_in[4];
    const float* b2    = (const float*)d_in[5];
    float* out = (float*)d_out;

    uint4* w2f = (uint4*)d_ws;                          // 512 KiB
    uint4* w1f = (uint4*)((char*)d_ws + 512 * 1024);    // 64 KiB

    hipLaunchKernelGGL(ffq_prep, dim3(144), dim3(256), 0, stream,
                       w2, w1, w2f, w1f);
    hipLaunchKernelGGL(ffq_mfma, dim3(2 * T_TOT / TB), dim3(512), 0, stream,
                       x, theta, b1, b2,
                       (const bf16x8*)w1f, (const bf16x8*)w2f, out);
}

// Round 6
// 27.064 us; speedup vs baseline: 5.3879x; 1.0442x over previous
//
#include <hip/hip_runtime.h>
#include <math.h>

typedef __attribute__((ext_vector_type(8))) short bf16x8;
typedef __attribute__((ext_vector_type(4))) float f32x4;

#define T_TOT 16384
#define E_ 256
#define FF_ 1024
#define NQ 10
#define TB 64
#define CH 256           // f per chunk
#define NCHUNK (FF_ / CH)
#define HGRAN (TB * CH)  // shorts per hs buffer (16384 = 32 KiB)

__device__ __forceinline__ unsigned short f2bf(float f) {
    unsigned u = __builtin_bit_cast(unsigned, f);
    u = (u + 0x7FFFu + ((u >> 16) & 1u)) >> 16;
    return (unsigned short)u;
}

// ---------------------------------------------------------------------------
// Prep (coalesced): bf16 MFMA B-fragments for w2 and w1^T.
//   thread id<32768: n = id>>7, k0 = (id&127)*8  -> wave reads 2 KiB contig.
//   writes granule w2f[(kk*16+nt)*64 + g*16 + lr], kk=k0>>5, g=(k0>>3)&3.
// ---------------------------------------------------------------------------
__global__ __launch_bounds__(256) void ffq_prep(
    const float* __restrict__ w2, const float* __restrict__ w1,
    uint4* __restrict__ w2f, uint4* __restrict__ w1f)
{
    int id = blockIdx.x * 256 + threadIdx.x;
    if (id < 32768) {
        int n  = id >> 7;
        int k0 = (id & 127) * 8;
        const float4* s = (const float4*)(w2 + (size_t)n * FF_ + k0);
        float4 a = s[0], b = s[1];
        uint4 v;
        v.x = f2bf(a.x) | ((unsigned)f2bf(a.y) << 16);
        v.y = f2bf(a.z) | ((unsigned)f2bf(a.w) << 16);
        v.z = f2bf(b.x) | ((unsigned)f2bf(b.y) << 16);
        v.w = f2bf(b.z) | ((unsigned)f2bf(b.w) << 16);
        int idx = ((k0 >> 5) * 16 + (n >> 4)) * 64 + ((k0 >> 3) & 3) * 16 + (n & 15);
        w2f[idx] = v;
    } else if (id < 32768 + 4096) {
        int id2 = id - 32768;
        int l = id2 & 63, nt = id2 >> 6;
        int n = nt * 16 + (l & 15);
        int g = l >> 4;
        unsigned short o[8];
#pragma unroll
        for (int j = 0; j < 8; ++j) {
            int k = g * 8 + j;
            o[j] = (k < NQ) ? f2bf(w1[n * NQ + k]) : (unsigned short)0;
        }
        uint4 v;
        v.x = o[0] | ((unsigned)o[1] << 16);
        v.y = o[2] | ((unsigned)o[3] << 16);
        v.z = o[4] | ((unsigned)o[5] << 16);
        v.w = o[6] | ((unsigned)o[7] << 16);
        w1f[id2] = v;
    }
}

// ---------------------------------------------------------------------------
// Fused kernel v4:
//  - grid 512 = 256 token-tiles x 2 col-halves; 8 waves; wave = 64 tok x 16 col.
//  - hs DOUBLE-buffered (2x32 KiB): 1 barrier/chunk; h(c+1) overlaps out(c).
//  - w1f depth-1 prefetch; B depth-1 register prefetch.
// ---------------------------------------------------------------------------
__global__ __launch_bounds__(512, 4) void ffq_mfma(
    const float* __restrict__ x, const float* __restrict__ theta,
    const float* __restrict__ b1, const float* __restrict__ b2,
    const bf16x8* __restrict__ w1f, const bf16x8* __restrict__ w2f,
    float* __restrict__ out)
{
    __shared__ unsigned short q_s[4 * 64 * 8];      // 4 KiB
    __shared__ unsigned short hs[2 * HGRAN];        // 64 KiB (double buffer)

    const int tid  = threadIdx.x;
    const int l    = tid & 63;
    const int wv   = tid >> 6;           // 0..7
    const int lr   = l & 15;
    const int g    = l >> 4;             // 0..3
    const int chb  = blockIdx.x & 1;     // col half 0/1
    const int tb   = (blockIdx.x >> 1) * TB;
    const int ncol = chb * 8 + wv;       // global col-tile 0..15

    // ---- Phase 0: threads 0..63 compute q, write B-frag granules ----
    if (tid < TB) {
        const int t = tb + tid;
        float xv[NQ];
        {
            float4 a = *(const float4*)(x + (size_t)t * E_);
            float4 b = *(const float4*)(x + (size_t)t * E_ + 4);
            float2 c = *(const float2*)(x + (size_t)t * E_ + 8);
            xv[0]=a.x; xv[1]=a.y; xv[2]=a.z; xv[3]=a.w;
            xv[4]=b.x; xv[5]=b.y; xv[6]=b.z; xv[7]=b.w;
            xv[8]=c.x; xv[9]=c.y;
        }
        float mm[NQ];
#pragma unroll
        for (int w = 0; w < NQ; ++w) mm[w] = cosf(theta[w]) * cosf(xv[w]);
        float qv[NQ];
        {
            float p = mm[0];
#pragma unroll
            for (int w = 1; w < NQ; ++w) { p *= mm[w]; qv[w] = p; }
            float p0 = mm[1];
#pragma unroll
            for (int w = 2; w < NQ; ++w) p0 *= mm[w];
            qv[0] = p0;
        }
        unsigned short qb[10];
#pragma unroll
        for (int k = 0; k < NQ; ++k) qb[k] = f2bf(qv[k]);
        uint4 s0, s1;
        s0.x = qb[0] | ((unsigned)qb[1] << 16);
        s0.y = qb[2] | ((unsigned)qb[3] << 16);
        s0.z = qb[4] | ((unsigned)qb[5] << 16);
        s0.w = qb[6] | ((unsigned)qb[7] << 16);
        s1.x = qb[8] | ((unsigned)qb[9] << 16);
        s1.y = 0; s1.z = 0; s1.w = 0;
        int tt = tid >> 4, r = tid & 15;
        uint4* base = (uint4*)q_s + tt * 64;
        base[r]      = s0;
        base[16 + r] = s1;
        base[32 + r] = make_uint4(0, 0, 0, 0);
        base[48 + r] = make_uint4(0, 0, 0, 0);
    }
    __syncthreads();

    bf16x8 qf[4];
#pragma unroll
    for (int tt = 0; tt < 4; ++tt) qf[tt] = ((const bf16x8*)q_s)[tt * 64 + l];

    f32x4 acc[4];
#pragma unroll
    for (int tt = 0; tt < 4; ++tt) acc[tt] = (f32x4){0.f, 0.f, 0.f, 0.f};

    // ---- h-phase macro body (chunk cc -> buffer hdst, weights wfa) ----
#define H_PHASE(cc, hdst, wfa)                                                 \
    {                                                                          \
        _Pragma("unroll")                                                      \
        for (int fi = 0; fi < 2; ++fi) {                                       \
            const int ftl = wv * 2 + fi;                                       \
            const int ntg = (cc) * 16 + ftl;                                   \
            const int f0  = ntg * 16 + g * 4;                                  \
            float4 bb = *(const float4*)(b1 + f0);                             \
            const int fl   = ftl * 16 + g * 4;                                 \
            const int sl   = (fl & 31) >> 3;                                   \
            const int gran = (fl >> 5) * 64 + lr + 16 * sl;                    \
            _Pragma("unroll")                                                  \
            for (int tt = 0; tt < 4; ++tt) {                                   \
                f32x4 d = {0.f, 0.f, 0.f, 0.f};                                \
                d = __builtin_amdgcn_mfma_f32_16x16x32_bf16(                   \
                        (wfa)[fi], qf[tt], d, 0, 0, 0);                        \
                unsigned p0 = f2bf(fmaxf(d[0] + bb.x, 0.f))                    \
                            | ((unsigned)f2bf(fmaxf(d[1] + bb.y, 0.f)) << 16); \
                unsigned p1 = f2bf(fmaxf(d[2] + bb.z, 0.f))                    \
                            | ((unsigned)f2bf(fmaxf(d[3] + bb.w, 0.f)) << 16); \
                unsigned byteoff = (unsigned)(tt * 512 + gran) * 16u           \
                                 + (unsigned)(fl & 7) * 2u;                    \
                *(uint2*)((char*)(hdst) + byteoff) = make_uint2(p0, p1);       \
            }                                                                  \
        }                                                                      \
    }

    // ---- prologue: chunk 0 h-phase into buf0 ----
    {
        bf16x8 wf0[2];
        wf0[0] = w1f[(0 * 16 + wv * 2 + 0) * 64 + l];
        wf0[1] = w1f[(0 * 16 + wv * 2 + 1) * 64 + l];
        H_PHASE(0, hs, wf0)
    }
    bf16x8 bcur = w2f[(0 * 16 + ncol) * 64 + l];
    __syncthreads();

    for (int c = 0; c < NCHUNK; ++c) {
        const int cur = c & 1;
        const unsigned short* hcur = hs + cur * HGRAN;
        unsigned short*       hnxt = hs + (cur ^ 1) * HGRAN;

        // prefetch next chunk's w1 granules (land during out-phase)
        const int cn = (c < NCHUNK - 1) ? c + 1 : NCHUNK - 1;
        bf16x8 wfn[2];
        wfn[0] = w1f[(cn * 16 + wv * 2 + 0) * 64 + l];
        wfn[1] = w1f[(cn * 16 + wv * 2 + 1) * 64 + l];

        // ---- out-phase: 8 kk steps, B prefetched 1 ahead ----
#pragma unroll
        for (int kkl = 0; kkl < 8; ++kkl) {
            const int kk  = c * 8 + kkl;
            const int kkn = (kk + 1 < 32) ? kk + 1 : 31;
            bf16x8 bnext = w2f[(kkn * 16 + ncol) * 64 + l];
            bf16x8 af[4];
#pragma unroll
            for (int tt = 0; tt < 4; ++tt)
                af[tt] = ((const bf16x8*)hcur)[(tt * 8 + kkl) * 64 + l];
#pragma unroll
            for (int tt = 0; tt < 4; ++tt)
                acc[tt] = __builtin_amdgcn_mfma_f32_16x16x32_bf16(
                    af[tt], bcur, acc[tt], 0, 0, 0);
            bcur = bnext;
        }

        // ---- h-phase for chunk c+1 into the other buffer (overlaps out) ----
        if (c < NCHUNK - 1) {
            H_PHASE(c + 1, hnxt, wfn)
        }
        __syncthreads();
    }
#undef H_PHASE

    // ---- epilogue: + b2, store fp32 ----
    {
        const int col = ncol * 16 + lr;
        const float bbv = b2[col];
#pragma unroll
        for (int tt = 0; tt < 4; ++tt) {
#pragma unroll
            for (int r = 0; r < 4; ++r) {
                int tr = tb + tt * 16 + g * 4 + r;
                out[(size_t)tr * E_ + col] = acc[tt][r] + bbv;
            }
        }
    }
}

extern "C" void kernel_launch(void* const* d_in, const int* in_sizes, int n_in,
                              void* d_out, int out_size, void* d_ws, size_t ws_size,
                              hipStream_t stream) {
    const float* x     = (const float*)d_in[0];
    const float* theta = (const float*)d_in[1];
    const float* w1    = (const float*)d_in[2];
    const float* b1    = (const float*)d_in[3];
    const float* w2    = (const float*)d_in[4];
    const float* b2    = (const float*)d_in[5];
    float* out = (float*)d_out;

    uint4* w2f = (uint4*)d_ws;                          // 512 KiB
    uint4* w1f = (uint4*)((char*)d_ws + 512 * 1024);    // 64 KiB

    hipLaunchKernelGGL(ffq_prep, dim3(144), dim3(256), 0, stream,
                       w2, w1, w2f, w1f);
    hipLaunchKernelGGL(ffq_mfma, dim3(2 * T_TOT / TB), dim3(512), 0, stream,
                       x, theta, b1, b2,
                       (const bf16x8*)w1f, (const bf16x8*)w2f, out);
}